// Round 6
// baseline (104.227 us; speedup 1.0000x reference)
//
#include <hip/hip_runtime.h>

// out[b,g] = sum_n x[b,g,n] * W[g,n] + bias[g]
// x: [16384, 368, 16] f32 (386 MB streamed once), W: [368,16] f32 (L1-hot),
// bias: [368] f32, out: [16384,368] f32 (24 MB).
//
// MLP-bound (R5: 4->8 outstanding lines/thread cut 89->78 us). This round:
// 16 outstanding. Each thread owns 4 rows spaced quarter = out_size/4
// = 368*4096 apart -> all share g (one W row). All 16 global_load_dwordx4
// issued before any FMA. No NT (R4: nt loads +35% slower). 64 B/lane coalesced.

#define NGROUPS 368

typedef float vfloat4 __attribute__((ext_vector_type(4)));

__global__ __launch_bounds__(256) void ensemble_kernel(
    const vfloat4* __restrict__ x4,
    const vfloat4* __restrict__ w4,
    const float* __restrict__ bias,
    float* __restrict__ out,
    int quarter)                 // = out_size/4 = 1,507,328 (= 368*4096)
{
    const int o = blockIdx.x * 256 + threadIdx.x;
    if (o >= quarter) return;

    const int g = o % NGROUPS;   // same g for all 4 rows (quarter % 368 == 0)

    // W row + bias first (L1 hits, returned early by in-order vmcnt)
    const vfloat4 w0 = w4[(g << 2) + 0];
    const vfloat4 w1 = w4[(g << 2) + 1];
    const vfloat4 w2 = w4[(g << 2) + 2];
    const vfloat4 w3 = w4[(g << 2) + 3];
    const float bg = bias[g];

    // ---- issue all 16 x-loads back-to-back (16-deep MLP) ----
    const vfloat4* xp0 = x4 + ((size_t)o << 2);
    const vfloat4* xp1 = xp0 + ((size_t)quarter << 2);
    const vfloat4* xp2 = xp1 + ((size_t)quarter << 2);
    const vfloat4* xp3 = xp2 + ((size_t)quarter << 2);
    const vfloat4 a0 = xp0[0], a1 = xp0[1], a2 = xp0[2], a3 = xp0[3];
    const vfloat4 b0 = xp1[0], b1 = xp1[1], b2 = xp1[2], b3 = xp1[3];
    const vfloat4 c0 = xp2[0], c1 = xp2[1], c2 = xp2[2], c3 = xp2[3];
    const vfloat4 d0 = xp3[0], d1 = xp3[1], d2 = xp3[2], d3 = xp3[3];

    float s0 = a0.x*w0.x + a0.y*w0.y + a0.z*w0.z + a0.w*w0.w
             + a1.x*w1.x + a1.y*w1.y + a1.z*w1.z + a1.w*w1.w
             + a2.x*w2.x + a2.y*w2.y + a2.z*w2.z + a2.w*w2.w
             + a3.x*w3.x + a3.y*w3.y + a3.z*w3.z + a3.w*w3.w;

    float s1 = b0.x*w0.x + b0.y*w0.y + b0.z*w0.z + b0.w*w0.w
             + b1.x*w1.x + b1.y*w1.y + b1.z*w1.z + b1.w*w1.w
             + b2.x*w2.x + b2.y*w2.y + b2.z*w2.z + b2.w*w2.w
             + b3.x*w3.x + b3.y*w3.y + b3.z*w3.z + b3.w*w3.w;

    float s2 = c0.x*w0.x + c0.y*w0.y + c0.z*w0.z + c0.w*w0.w
             + c1.x*w1.x + c1.y*w1.y + c1.z*w1.z + c1.w*w1.w
             + c2.x*w2.x + c2.y*w2.y + c2.z*w2.z + c2.w*w2.w
             + c3.x*w3.x + c3.y*w3.y + c3.z*w3.z + c3.w*w3.w;

    float s3 = d0.x*w0.x + d0.y*w0.y + d0.z*w0.z + d0.w*w0.w
             + d1.x*w1.x + d1.y*w1.y + d1.z*w1.z + d1.w*w1.w
             + d2.x*w2.x + d2.y*w2.y + d2.z*w2.z + d2.w*w2.w
             + d3.x*w3.x + d3.y*w3.y + d3.z*w3.z + d3.w*w3.w;

    out[o]               = s0 + bg;
    out[o +   quarter]   = s1 + bg;
    out[o + 2*quarter]   = s2 + bg;
    out[o + 3*quarter]   = s3 + bg;
}

extern "C" void kernel_launch(void* const* d_in, const int* in_sizes, int n_in,
                              void* d_out, int out_size, void* d_ws, size_t ws_size,
                              hipStream_t stream)
{
    const vfloat4* x4  = (const vfloat4*)d_in[0];
    const vfloat4* w4  = (const vfloat4*)d_in[1];
    const float* bias  = (const float*)d_in[2];
    float* out = (float*)d_out;

    const int quarter = out_size / 4;            // 1,507,328 = 368*4096
    const int blocks = (quarter + 255) / 256;    // 5888 exact

    ensemble_kernel<<<blocks, 256, 0, stream>>>(x4, w4, bias, out, quarter);
}